// Round 11
// baseline (95.841 us; speedup 1.0000x reference)
//
#include <hip/hip_runtime.h>

// ConvSSM scan, spatial domain, QUAD step-doubling (A^4, 16 serial steps).
//   h_t = A (*) h_{t-1} + u_t,  u_t = B (*) xpad_t,  (*) = circular conv on 64x64.
// S_m = h_{4m+3}, S_{-1} = 0:
//   S_m      = A4 (*) S_{m-1} + G4_m,  A4 = A^4 (9x9)
//   G4_m     = c3 where c0 = u_{4m}, c_k = A (*) c_{k-1} + u_{4m+k}
//   h_{4m+k} = A^{k+1} (*) S_{m-1} + c_k   (k=0,1,2; crop)
//   h_{4m+3} = S_m (crop)
// pass1q (1088 blocks): G4_m (40x40) -> ws (+ zero pad tile m=16; + per-channel
//   A^2/A^3/A^4 coefficient table from the m==0,b==0 blocks).
// scanq  (64 blocks x 512 thr): 16-step A4 scan, h in LDS dbuf, 1x... 2 rows x
//   4 cols/thread, 10x12 window streamed (col halo via chained DPP row_ror:1),
//   stores S_m (40 halo rows x 64 cols) to ws. NO output writes.
// emitq  (1024 blocks x 256 thr): per (m,bc): recompute c0..c2 cascade from x,
//   stage S_{m-1}, emit h_{4m..4m+3}. Fully parallel (4 blocks/CU).

constexpr int T_STEPS = 64;
constexpr int B_DIM   = 2;
constexpr int C_DIM   = 32;
constexpr int HW      = 32;
constexpr int N       = 64;
constexpr int NIMG    = B_DIM * C_DIM;   // 64
constexpr int MQ      = 16;              // quad steps
constexpr int HSTR    = 68;              // LDS row stride (floats)
constexpr int G4ROW   = 40;
constexpr int G4SZT   = 40 * 40;         // 1600 floats per tile
constexpr int SROWS   = 40;              // stored S rows: 0..31 and 56..63
constexpr int SSZT    = SROWS * 64;      // 2560 floats per state
// coef layout per channel (stride 160): [0..24]=A^2, [25..73]=A^3, [74..154]=A^4
constexpr int CO_A2 = 0, CO_A3 = 25, CO_A4 = 74, CO_STRIDE = 160;

__device__ __forceinline__ float rfl(float v) {
    return __int_as_float(__builtin_amdgcn_readfirstlane(__float_as_int(v)));
}
// dst lane g receives src lane (g-1)&15 within each 16-lane DPP row (row_ror:1)
__device__ __forceinline__ float ror1(float x) {
    return __int_as_float(__builtin_amdgcn_update_dpp(
        0, __float_as_int(x), 0x121, 0xF, 0xF, false));
}

// One cascade stage: dst(y,x) [SO x SO, row stride 40] =
//   sum bw[ky][kx]*xsf[y-ky][x-kx]  (xsf 32x32 valid)
// + sum a[ky][kx] *src[y-ky][x-kx]  (src SI x SI valid; SI==0 -> skip)
__device__ __forceinline__ void cascade_stage(
    float* __restrict__ dst, const float* __restrict__ src, int SI, int SO,
    const float (*xsf)[36], const float* a9, const float* bw9,
    int tid, int nthr)
{
    const int niter = SO * 10;
    for (int i4 = tid; i4 < niter; i4 += nthr) {
        const int y  = i4 / 10;
        const int x0 = (i4 - y * 10) * 4;
        float r[4] = {0.f, 0.f, 0.f, 0.f};
#pragma unroll
        for (int ky = 0; ky < 3; ++ky) {
            const int yy = y - ky;
            if (yy >= 0 && yy < 32) {
                float xr[6];
#pragma unroll
                for (int d = 0; d < 6; ++d) {
                    const int xq = x0 - 2 + d;
                    xr[d] = (xq >= 0 && xq < 32) ? xsf[yy][xq] : 0.f;
                }
#pragma unroll
                for (int kx = 0; kx < 3; ++kx) {
                    const float cf = bw9[ky * 3 + kx];
#pragma unroll
                    for (int j = 0; j < 4; ++j) r[j] += cf * xr[2 + j - kx];
                }
            }
            if (SI > 0 && yy >= 0 && yy < SI) {
                float sr[6];
#pragma unroll
                for (int d = 0; d < 6; ++d) {
                    const int xq = x0 - 2 + d;
                    sr[d] = (xq >= 0 && xq < SI) ? src[yy * 40 + xq] : 0.f;
                }
#pragma unroll
                for (int kx = 0; kx < 3; ++kx) {
                    const float cf = a9[ky * 3 + kx];
#pragma unroll
                    for (int j = 0; j < 4; ++j) r[j] += cf * sr[2 + j - kx];
                }
            }
        }
        *(float4*)(dst + y * 40 + x0) = make_float4(r[0], r[1], r[2], r[3]);
    }
}

// ---------------- Pass 1: G4_m per (m, bc) + coeff table ---------------------
__global__ __launch_bounds__(256)
void convssm_pass1q(const float* __restrict__ x_seq,  // (T,B,C,32,32)
                    const float* __restrict__ A_k,    // (C,3,3)
                    const float* __restrict__ B_k,    // (C,3,3)
                    float* __restrict__ G4,           // (NIMG*17, 40,40) idx bc*17+m
                    float* __restrict__ coef)         // (32, 160)
{
    __shared__ __align__(16) float xs[4][32][36];
    __shared__ __align__(16) float bufA[38 * 40];
    __shared__ __align__(16) float bufB[36 * 40];
    __shared__ float a2l[25];

    const int blk = blockIdx.x;           // m*64 + bc, m in [0,16]
    const int m   = blk >> 6;
    const int bc  = blk & 63;
    const int c   = bc & 31;
    const int tid = threadIdx.x;

    float* Gg = G4 + (size_t)(bc * (MQ + 1) + m) * G4SZT;
    const float4 z4 = make_float4(0.f, 0.f, 0.f, 0.f);

    if (m == MQ) {   // pad tile for branchless scan prefetch
        for (int i4 = tid; i4 < 400; i4 += 256)
            *(float4*)(Gg + i4 * 4) = z4;
        return;
    }

    float a[9], bw[9];
#pragma unroll
    for (int i = 0; i < 9; ++i) {
        a[i]  = rfl(A_k[c * 9 + i]);
        bw[i] = rfl(B_k[c * 9 + i]);
    }

    // stage 4 x frames
    {
        const int y  = tid >> 3;
        const int x4 = (tid & 7) * 4;
#pragma unroll
        for (int f = 0; f < 4; ++f) {
            const float* xp = x_seq + ((size_t)(4 * m + f) * NIMG + bc) * (HW * HW);
            *(float4*)&xs[f][y][x4] = *(const float4*)(xp + y * HW + x4);
        }
    }
    __syncthreads();

    cascade_stage(bufA, nullptr, 0, 34, xs[0], a, bw, tid, 256);   // c0
    __syncthreads();
    cascade_stage(bufB, bufA, 34, 36, xs[1], a, bw, tid, 256);     // c1
    __syncthreads();
    cascade_stage(bufA, bufB, 36, 38, xs[2], a, bw, tid, 256);     // c2
    __syncthreads();
    cascade_stage(Gg,   bufA, 38, 40, xs[3], a, bw, tid, 256);     // G4 (global)

    // per-channel coefficient table (one block per channel: m==0, b==0)
    if (m == 0 && bc < 32) {
        __syncthreads();
        if (tid < 25) {   // A^2 (5x5)
            const int p = tid / 5, q = tid - (tid / 5) * 5;
            float v = 0.f;
            for (int ky = 0; ky < 3; ++ky)
                for (int kx = 0; kx < 3; ++kx) {
                    const int py = p - ky, qx = q - kx;
                    if (py >= 0 && py < 3 && qx >= 0 && qx < 3)
                        v += a[ky * 3 + kx] * a[py * 3 + qx];
                }
            a2l[tid] = v;
            coef[c * CO_STRIDE + CO_A2 + tid] = v;
        }
        __syncthreads();
        if (tid < 49) {   // A^3 = A^2 * A (7x7)
            const int p = tid / 7, q = tid - (tid / 7) * 7;
            float v = 0.f;
            for (int i = 0; i < 5; ++i)
                for (int j = 0; j < 5; ++j) {
                    const int py = p - i, qx = q - j;
                    if (py >= 0 && py < 3 && qx >= 0 && qx < 3)
                        v += a2l[i * 5 + j] * a[py * 3 + qx];
                }
            coef[c * CO_STRIDE + CO_A3 + tid] = v;
        }
        if (tid >= 64 && tid < 145) {   // A^4 = A^2 * A^2 (9x9), separate threads
            const int t = tid - 64;
            const int p = t / 9, q = t - (t / 9) * 9;
            float v = 0.f;
            for (int i = 0; i < 5; ++i)
                for (int j = 0; j < 5; ++j) {
                    const int py = p - i, qx = q - j;
                    if (py >= 0 && py < 5 && qx >= 0 && qx < 5)
                        v += a2l[i * 5 + j] * a2l[py * 5 + qx];
                }
            coef[c * CO_STRIDE + CO_A4 + t] = v;
        }
    }
}

// ---------------- Pass 2: 16-step A^4 scan, 512 threads ----------------------
__global__ __launch_bounds__(512, 2)
void convssm_scanq(const float* __restrict__ G4,
                   const float* __restrict__ coef,
                   float* __restrict__ S)            // (NIMG*16, 40, 64)
{
    __shared__ __align__(16) float hbuf[2][N * HSTR];

    const int bc  = blockIdx.x;          // 0..63
    const int c   = bc & 31;
    const int tid = threadIdx.x;
    const int g   = tid & 15;            // col group: cols 4g..4g+3
    const int s   = tid >> 4;            // 0..31: rows 2s, 2s+1
    const int y0  = s * 2;
    const int xc  = g * 4;

    float a4[81];
    {
        const float* cb = coef + c * CO_STRIDE + CO_A4;
#pragma unroll
        for (int i = 0; i < 81; ++i) a4[i] = rfl(cb[i]);
    }

    for (int i = tid; i < N * HSTR; i += 512) hbuf[0][i] = 0.0f;

    const bool  gok = (y0 < G4ROW) && (xc < G4ROW);
    const float* Gb = G4 + (size_t)bc * (MQ + 1) * G4SZT + y0 * G4ROW + xc;

    const float4 z4 = make_float4(0.f, 0.f, 0.f, 0.f);
    float4 gc0 = z4, gc1 = z4;
    if (gok) {
        gc0 = *(const float4*)(Gb);
        gc1 = *(const float4*)(Gb + G4ROW);
    }

    float* hold = &hbuf[0][0];
    float* hnew = &hbuf[1][0];
    float* Sb   = S + (size_t)bc * MQ * SSZT;
    const bool sok  = (y0 < 32) || (y0 >= 56);
    const int  slot = (y0 < 32) ? y0 : (y0 - 24);

    float4 acc0 = z4, acc1 = z4;   // own rows y0, y0+1 (cols xc..xc+3)

    __syncthreads();

    for (int m = 0; m < MQ; ++m) {
        // prefetch next G4 tile (pad at m=16 -> branchless)
        float4 gn0 = z4, gn1 = z4;
        if (gok) {
            const float* p = Gb + (size_t)(m + 1) * G4SZT;
            gn0 = *(const float4*)(p);
            gn1 = *(const float4*)(p + G4ROW);
        }

        float o0[4] = {gc0.x, gc0.y, gc0.z, gc0.w};
        float o1[4] = {gc1.x, gc1.y, gc1.z, gc1.w};

        // stream 10 window rows (abs rows y0-8 .. y0+1), 12 cols xc-8..xc+3:
        // w[8..11] direct, w[4..7] = ror1 (lane g-1), w[0..3] = ror1^2 (g-2).
#pragma unroll
        for (int i = 0; i < 10; ++i) {
            float4 d4;
            if (i < 8) {
                const int rr = (y0 + 56 + i) & 63;
                d4 = *(const float4*)(hold + rr * HSTR + xc);
            } else {
                d4 = (i == 8) ? acc0 : acc1;
            }
            float w[12];
            w[8] = d4.x; w[9] = d4.y; w[10] = d4.z; w[11] = d4.w;
            w[4] = ror1(d4.x); w[5] = ror1(d4.y); w[6] = ror1(d4.z); w[7] = ror1(d4.w);
            w[0] = ror1(w[4]); w[1] = ror1(w[5]); w[2] = ror1(w[6]); w[3] = ror1(w[7]);

            if (i <= 8) {                 // out row y0: tap row p = 8 - i
                const int p = 8 - i;
#pragma unroll
                for (int q = 0; q < 9; ++q) {
                    const float cf = a4[p * 9 + q];
#pragma unroll
                    for (int j = 0; j < 4; ++j) o0[j] += cf * w[8 + j - q];
                }
            }
            if (i >= 1) {                 // out row y0+1: tap row p = 9 - i
                const int p = 9 - i;
#pragma unroll
                for (int q = 0; q < 9; ++q) {
                    const float cf = a4[p * 9 + q];
#pragma unroll
                    for (int j = 0; j < 4; ++j) o1[j] += cf * w[8 + j - q];
                }
            }
        }
        const float4 accn0 = make_float4(o0[0], o0[1], o0[2], o0[3]);
        const float4 accn1 = make_float4(o1[0], o1[1], o1[2], o1[3]);

        *(float4*)(hnew + y0 * HSTR + xc)       = accn0;
        *(float4*)(hnew + (y0 + 1) * HSTR + xc) = accn1;
        if (sok) {
            float* sp = Sb + (size_t)m * SSZT + slot * 64 + xc;
            *(float4*)(sp)      = accn0;
            *(float4*)(sp + 64) = accn1;
        }

        __syncthreads();

        float* t = hold; hold = hnew; hnew = t;
        acc0 = accn0; acc1 = accn1;
        gc0 = gn0; gc1 = gn1;
    }
}

// ---------------- Pass 3: parallel emit, one block per (m, bc) ---------------
__global__ __launch_bounds__(256)
void convssm_emitq(const float* __restrict__ x_seq,
                   const float* __restrict__ A_k,
                   const float* __restrict__ B_k,
                   const float* __restrict__ coef,
                   const float* __restrict__ S,
                   float* __restrict__ out)          // (T,B,C,32,32)
{
    __shared__ __align__(16) float Sl[SROWS][68];
    __shared__ __align__(16) float xs[3][32][36];
    __shared__ __align__(16) float c0b[34 * 40];
    __shared__ __align__(16) float c1b[36 * 40];
    __shared__ __align__(16) float c2b[38 * 40];
    __shared__ float cl[96];   // [0..24]=A^2, [25..73]=A^3

    const int blk = blockIdx.x;           // m*64 + bc, m in [0,16)
    const int m   = blk >> 6;
    const int bc  = blk & 63;
    const int c   = bc & 31;
    const int tid = threadIdx.x;

    float a[9], bw[9];
#pragma unroll
    for (int i = 0; i < 9; ++i) {
        a[i]  = rfl(A_k[c * 9 + i]);
        bw[i] = rfl(B_k[c * 9 + i]);
    }
    if (tid < 74) cl[tid] = coef[c * CO_STRIDE + tid];

    // stage x_{4m..4m+2}
    {
        const int y  = tid >> 3;
        const int x4 = (tid & 7) * 4;
#pragma unroll
        for (int f = 0; f < 3; ++f) {
            const float* xp = x_seq + ((size_t)(4 * m + f) * NIMG + bc) * (HW * HW);
            *(float4*)&xs[f][y][x4] = *(const float4*)(xp + y * HW + x4);
        }
    }
    // stage S_{m-1} (40 stored rows x 64 cols)
    if (m > 0) {
        const float* Sp = S + (size_t)(bc * MQ + (m - 1)) * SSZT;
        for (int i4 = tid; i4 < 640; i4 += 256) {
            const int y  = i4 >> 4;
            const int x4 = (i4 & 15) * 4;
            *(float4*)&Sl[y][x4] = *(const float4*)(Sp + y * 64 + x4);
        }
    }
    __syncthreads();

    cascade_stage(c0b, nullptr, 0, 34, xs[0], a, bw, tid, 256);
    __syncthreads();
    cascade_stage(c1b, c0b, 34, 36, xs[1], a, bw, tid, 256);
    __syncthreads();
    cascade_stage(c2b, c1b, 36, 38, xs[2], a, bw, tid, 256);
    __syncthreads();

    // emit: 4 px per thread (row y, cols x0..x0+3)
    const int y  = tid >> 3;              // 0..31
    const int x0 = (tid & 7) * 4;         // 0..28

    float4 i0 = *(const float4*)(c0b + y * 40 + x0);
    float4 i1 = *(const float4*)(c1b + y * 40 + x0);
    float4 i2 = *(const float4*)(c2b + y * 40 + x0);
    float e0[4] = {i0.x, i0.y, i0.z, i0.w};
    float e1[4] = {i1.x, i1.y, i1.z, i1.w};
    float e2[4] = {i2.x, i2.y, i2.z, i2.w};

    if (m > 0) {
        const int xm8 = (x0 + 56) & 63;
        const int xm4 = (x0 + 60) & 63;
#pragma unroll
        for (int i = 0; i < 7; ++i) {     // abs row y-6+i
            const int rr   = (y + 58 + i) & 63;
            const int slot = (rr < 32) ? rr : (rr - 24);
            const float4 l4 = *(const float4*)(&Sl[slot][xm8]);
            const float4 m4 = *(const float4*)(&Sl[slot][xm4]);
            const float4 d4 = *(const float4*)(&Sl[slot][x0]);
            float w[12] = {l4.x, l4.y, l4.z, l4.w,
                           m4.x, m4.y, m4.z, m4.w,
                           d4.x, d4.y, d4.z, d4.w};
            {   // A^3 contribution: p = 6 - i (0..6)
                const int p = 6 - i;
#pragma unroll
                for (int q = 0; q < 7; ++q) {
                    const float cf = cl[CO_A3 + p * 7 + q];
#pragma unroll
                    for (int j = 0; j < 4; ++j) e2[j] += cf * w[8 + j - q];
                }
            }
            if (i >= 2) {   // A^2: p = 6 - i (0..4)
                const int p = 6 - i;
#pragma unroll
                for (int q = 0; q < 5; ++q) {
                    const float cf = cl[CO_A2 + p * 5 + q];
#pragma unroll
                    for (int j = 0; j < 4; ++j) e1[j] += cf * w[8 + j - q];
                }
            }
            if (i >= 4) {   // A: p = 6 - i (0..2)
                const int p = 6 - i;
#pragma unroll
                for (int q = 0; q < 3; ++q) {
                    const float cf = a[p * 3 + q];
#pragma unroll
                    for (int j = 0; j < 4; ++j) e0[j] += cf * w[8 + j - q];
                }
            }
        }
    }

    // h_{4m+3} = crop(S_m)
    const float4 e3 = *(const float4*)(S + (size_t)(bc * MQ + m) * SSZT + y * 64 + x0);

    const size_t tstr = (size_t)NIMG * (HW * HW);  // 65536
    float* ob = out + (size_t)(4 * m) * tstr + (size_t)bc * (HW * HW) + y * HW + x0;
    *(float4*)(ob)            = make_float4(e0[0], e0[1], e0[2], e0[3]);
    *(float4*)(ob + tstr)     = make_float4(e1[0], e1[1], e1[2], e1[3]);
    *(float4*)(ob + 2 * tstr) = make_float4(e2[0], e2[1], e2[2], e2[3]);
    *(float4*)(ob + 3 * tstr) = e3;
}

// ---------------- Fallback (round-1 fused, known-correct) --------------------
__global__ __launch_bounds__(256)
void convssm_scan_fused(const float* __restrict__ x_seq,
                        const float* __restrict__ A_k,
                        const float* __restrict__ B_k,
                        float* __restrict__ out)
{
    __shared__ float h0[N][N];
    __shared__ float h1[N][N];
    __shared__ float xsf[N][N];

    const int bc = blockIdx.x;
    const int b  = bc >> 5;
    const int c  = bc & 31;
    const int tid = threadIdx.x;
    const int x   = tid & 63;
    const int y0  = (tid >> 6) << 4;

    float a[9], bw[9];
#pragma unroll
    for (int i = 0; i < 9; ++i) { a[i] = A_k[c*9+i]; bw[i] = B_k[c*9+i]; }
#pragma unroll
    for (int r = 0; r < 16; ++r) { h0[y0+r][x] = 0.f; xsf[y0+r][x] = 0.f; }

    float (*hold)[N] = h0;
    float (*hnew)[N] = h1;
    const int xm1 = (x + 63) & 63, xm2 = (x + 62) & 63;
    const size_t img = (size_t)HW*HW, tstr = (size_t)NIMG*img;
    const float* xbase = x_seq + ((size_t)b*C_DIM + c)*img;
    float* obase = out + ((size_t)b*C_DIM + c)*img;
    const bool loader = (x < HW);

    for (int t = 0; t < T_STEPS; ++t) {
        if (loader) {
#pragma unroll
            for (int r = 0; r < 16; ++r) {
                int yy = y0 + r;
                if (yy < HW) xsf[yy][x] = xbase[(size_t)t*tstr + yy*HW + x];
            }
        }
        __syncthreads();
        const int ym1 = (y0 + N - 1) & 63, ym2 = (y0 + N - 2) & 63;
        float hr1c0 = hold[ym1][x], hr1c1 = hold[ym1][xm1], hr1c2 = hold[ym1][xm2];
        float hr2c0 = hold[ym2][x], hr2c1 = hold[ym2][xm1], hr2c2 = hold[ym2][xm2];
        float sr1c0 = xsf[ym1][x], sr1c1 = xsf[ym1][xm1], sr1c2 = xsf[ym1][xm2];
        float sr2c0 = xsf[ym2][x], sr2c1 = xsf[ym2][xm1], sr2c2 = xsf[ym2][xm2];
#pragma unroll
        for (int r = 0; r < 16; ++r) {
            const int yy = y0 + r;
            float hr0c0 = hold[yy][x], hr0c1 = hold[yy][xm1], hr0c2 = hold[yy][xm2];
            float sr0c0 = xsf[yy][x], sr0c1 = xsf[yy][xm1], sr0c2 = xsf[yy][xm2];
            float v = a[0]*hr0c0 + a[1]*hr0c1 + a[2]*hr0c2
                    + a[3]*hr1c0 + a[4]*hr1c1 + a[5]*hr1c2
                    + a[6]*hr2c0 + a[7]*hr2c1 + a[8]*hr2c2
                    + bw[0]*sr0c0 + bw[1]*sr0c1 + bw[2]*sr0c2
                    + bw[3]*sr1c0 + bw[4]*sr1c1 + bw[5]*sr1c2
                    + bw[6]*sr2c0 + bw[7]*sr2c1 + bw[8]*sr2c2;
            hnew[yy][x] = v;
            if (yy < HW && x < HW) obase[(size_t)t*tstr + yy*HW + x] = v;
            hr2c0=hr1c0; hr2c1=hr1c1; hr2c2=hr1c2;
            hr1c0=hr0c0; hr1c1=hr0c1; hr1c2=hr0c2;
            sr2c0=sr1c0; sr2c1=sr1c1; sr2c2=sr1c2;
            sr1c0=sr0c0; sr1c1=sr0c1; sr1c2=sr0c2;
        }
        __syncthreads();
        float (*tmp)[N] = hold; hold = hnew; hnew = tmp;
    }
}

extern "C" void kernel_launch(void* const* d_in, const int* in_sizes, int n_in,
                              void* d_out, int out_size, void* d_ws, size_t ws_size,
                              hipStream_t stream)
{
    const float* x_seq = (const float*)d_in[0];
    const float* A_k   = (const float*)d_in[1];
    const float* B_k   = (const float*)d_in[2];
    float* out = (float*)d_out;

    const size_t nG4 = (size_t)NIMG * (MQ + 1) * G4SZT;   // floats
    const size_t nCF = 32 * CO_STRIDE;
    const size_t nS  = (size_t)NIMG * MQ * SSZT;
    const size_t need = (nG4 + nCF + nS) * sizeof(float); // ~17.5 MB

    if (ws_size >= need) {
        float* G4c = (float*)d_ws;
        float* cf  = G4c + nG4;
        float* Sg  = cf + nCF;
        convssm_pass1q<<<dim3((MQ + 1) * NIMG), dim3(256), 0, stream>>>(
            x_seq, A_k, B_k, G4c, cf);
        convssm_scanq<<<dim3(NIMG), dim3(512), 0, stream>>>(G4c, cf, Sg);
        convssm_emitq<<<dim3(MQ * NIMG), dim3(256), 0, stream>>>(
            x_seq, A_k, B_k, cf, Sg, out);
    } else {
        convssm_scan_fused<<<dim3(NIMG), dim3(256), 0, stream>>>(
            x_seq, A_k, B_k, out);
    }
}

// Round 12
// 81.608 us; speedup vs baseline: 1.1744x; 1.1744x over previous
//
#include <hip/hip_runtime.h>
#include <math.h>

// ConvSSM scan via 1-D frequency domain (rFFT along x only).
//   h_t = A (*) h_{t-1} + B (*) xpad_t, (*) = circular conv on 64x64.
// After rfft_x (64-point, 33 bins k):
//   hhat_t[y][k] = sum_{ky=0..2} Ahat[ky][k] * hhat_{t-1}[(y-ky)&63][k] + shat_t[y][k]
// i.e. pointwise in k, 3-tap circular conv in y. Per (image,bin) the scan is a
// 64-lane wave job: lane y holds hhat[y], neighbors via __shfl, NO LDS/barriers.
// fwd  (4096 blocks): DFT-x of x rows (reg-resident, incremental rotation) +
//       Bhat y-conv -> shat[bc][t][k][36]  (y valid 0..33)
// scan (528 blocks = 2112 waves): 64-step recurrence, 8-deep s prefetch ring,
//       writes hhat[t][bc][k][32] (crop rows only)
// inv  (4096 blocks): iDFT-x from 33 bins -> 32 cols, crop, write out.

constexpr int T_STEPS = 64;
constexpr int B_DIM   = 2;
constexpr int C_DIM   = 32;
constexpr int HW      = 32;
constexpr int N       = 64;
constexpr int NIMG    = B_DIM * C_DIM;   // 64
constexpr int KB      = 33;              // rfft bins along x
constexpr int SY      = 36;              // padded y slots in shat (valid 0..33)
constexpr int HY      = 32;              // stored y rows in hhat (crop)

constexpr float THETA = 0.09817477042468103f;   // 2*pi/64

// float2 element counts
constexpr size_t S_SZ = (size_t)NIMG * T_STEPS * KB * SY;  // 64*64*33*36
constexpr size_t H_SZ = (size_t)T_STEPS * NIMG * KB * HY;  // 64*64*33*32

// ---------------- fwd: DFT-x + Bhat y-conv -> shat ---------------------------
__global__ __launch_bounds__(256)
void convssm_fwd(const float* __restrict__ x_seq,   // (T,B,C,32,32)
                 const float* __restrict__ B_k,     // (C,3,3)
                 float2* __restrict__ Shat)         // [bc][t][k][SY]
{
    __shared__ __align__(16) float xs[32][36];
    __shared__ float2 Xl[32][33];
    __shared__ float2 bh[3][33];

    const int blk = blockIdx.x;          // t*64 + bc
    const int t   = blk >> 6;
    const int bc  = blk & 63;
    const int c   = bc & 31;
    const int tid = threadIdx.x;

    // stage x image (coalesced float4)
    {
        const float4* xp = (const float4*)(x_seq + (size_t)blk * (HW * HW));
        const int y  = tid >> 3;
        const int x4 = (tid & 7) * 4;
        *(float4*)&xs[y][x4] = xp[tid];
    }
    // Bhat[ky][k] = sum_j B[ky][j] e^{-2pi i jk/64}
    if (tid < 99) {
        const int ky = tid / 33, k = tid - ky * 33;
        const float b0 = B_k[c * 9 + ky * 3 + 0];
        const float b1 = B_k[c * 9 + ky * 3 + 1];
        const float b2 = B_k[c * 9 + ky * 3 + 2];
        float s1, c1;
        __sincosf((float)k * THETA, &s1, &c1);
        const float c2 = c1 * c1 - s1 * s1, s2 = 2.f * c1 * s1;
        bh[ky][k] = make_float2(b0 + b1 * c1 + b2 * c2, -(b1 * s1 + b2 * s2));
    }
    __syncthreads();

    // DFT-x: thread = (row y, bin group kg); bins k = kg + 8m, m=0..4 (k<33)
    {
        const int y  = tid >> 3;
        const int kg = tid & 7;
        float xr[32];
#pragma unroll
        for (int j = 0; j < 8; ++j) {
            const float4 v = *(const float4*)&xs[y][j * 4];
            xr[4 * j]     = v.x; xr[4 * j + 1] = v.y;
            xr[4 * j + 2] = v.z; xr[4 * j + 3] = v.w;
        }
        float cr[5], sr[5], cw[5], sw[5], Xre[5], Xim[5];
#pragma unroll
        for (int m = 0; m < 5; ++m) {
            const int k = kg + 8 * m;
            float s1, c1;
            __sincosf((float)k * THETA, &s1, &c1);
            cw[m] = c1; sw[m] = s1;
            cr[m] = 1.f; sr[m] = 0.f;
            Xre[m] = 0.f; Xim[m] = 0.f;
        }
#pragma unroll
        for (int n = 0; n < 32; ++n) {
            const float xv = xr[n];
#pragma unroll
            for (int m = 0; m < 5; ++m) {
                Xre[m] = fmaf(xv, cr[m], Xre[m]);
                Xim[m] = fmaf(-xv, sr[m], Xim[m]);
                const float cn = cr[m] * cw[m] - sr[m] * sw[m];
                const float sn = sr[m] * cw[m] + cr[m] * sw[m];
                cr[m] = cn; sr[m] = sn;
            }
        }
#pragma unroll
        for (int m = 0; m < 5; ++m) {
            const int k = kg + 8 * m;
            if (k < 33) Xl[y][k] = make_float2(Xre[m], Xim[m]);
        }
    }
    __syncthreads();

    // shat[y][k] = sum_ky bh[ky][k] * Xl[y-ky][k], y in [0,34)
    float2* Sb = Shat + ((size_t)(bc * T_STEPS + t)) * KB * SY;
    for (int i = tid; i < 33 * 34; i += 256) {
        const int k = i / 34;
        const int y = i - 34 * k;
        float re = 0.f, im = 0.f;
#pragma unroll
        for (int ky = 0; ky < 3; ++ky) {
            const int yy = y - ky;
            if (yy >= 0 && yy < 32) {
                const float2 b = bh[ky][k];
                const float2 X = Xl[yy][k];
                re += b.x * X.x - b.y * X.y;
                im += b.x * X.y + b.y * X.x;
            }
        }
        Sb[(size_t)k * SY + y] = make_float2(re, im);
    }
}

// ---------------- scan: per-(bc,k) wave, 64 steps, no barriers ----------------
__global__ __launch_bounds__(256)
void convssm_scanf(const float2* __restrict__ Shat,  // [bc][t][k][SY]
                   const float* __restrict__ A_k,    // (C,3,3)
                   float2* __restrict__ Hhat)        // [t][bc][k][HY]
{
    const int tid = threadIdx.x;
    const int wid = blockIdx.x * 4 + (tid >> 6);   // 0..2111
    const int y   = tid & 63;
    const int bc  = wid / 33;
    const int k   = wid - 33 * bc;
    const int c   = bc & 31;

    // Ahat[ky][k]
    float Are[3], Aim[3];
    {
        float s1, c1;
        __sincosf((float)k * THETA, &s1, &c1);
        const float c2 = c1 * c1 - s1 * s1, s2 = 2.f * c1 * s1;
#pragma unroll
        for (int ky = 0; ky < 3; ++ky) {
            const float a0 = A_k[c * 9 + ky * 3 + 0];
            const float a1 = A_k[c * 9 + ky * 3 + 1];
            const float a2 = A_k[c * 9 + ky * 3 + 2];
            Are[ky] = a0 + a1 * c1 + a2 * c2;
            Aim[ky] = -(a1 * s1 + a2 * s2);
        }
    }

    const int ym1 = (y + 63) & 63;
    const int ym2 = (y + 62) & 63;
    const bool sok = (y < 34);
    const bool hok = (y < HY);

    const float2* Sb = Shat + ((size_t)bc * T_STEPS) * KB * SY + (size_t)k * SY + y;
    const size_t sstep = (size_t)KB * SY;                    // per-t stride (float2)
    float2* Hb = Hhat + ((size_t)bc * KB + k) * HY + y;
    const size_t hstep = (size_t)NIMG * KB * HY;             // per-t stride (float2)

    const float2 z2 = make_float2(0.f, 0.f);
    float hre = 0.f, him = 0.f;

    float2 sc[8], sn[8];
#pragma unroll
    for (int j = 0; j < 8; ++j)
        sc[j] = sok ? Sb[(size_t)j * sstep] : z2;

    for (int ob = 0; ob < 8; ++ob) {
        const int t0 = ob * 8;
        const bool pf = sok && (ob < 7);
#pragma unroll
        for (int j = 0; j < 8; ++j)
            sn[j] = pf ? Sb[(size_t)(t0 + 8 + j) * sstep] : z2;
#pragma unroll
        for (int j = 0; j < 8; ++j) {
            const float h1re = __shfl(hre, ym1, 64);
            const float h1im = __shfl(him, ym1, 64);
            const float h2re = __shfl(hre, ym2, 64);
            const float h2im = __shfl(him, ym2, 64);
            float nre = sc[j].x, nim = sc[j].y;
            nre += Are[0] * hre - Aim[0] * him;
            nim += Are[0] * him + Aim[0] * hre;
            nre += Are[1] * h1re - Aim[1] * h1im;
            nim += Are[1] * h1im + Aim[1] * h1re;
            nre += Are[2] * h2re - Aim[2] * h2im;
            nim += Are[2] * h2im + Aim[2] * h2re;
            hre = nre; him = nim;
            if (hok) Hb[(size_t)(t0 + j) * hstep] = make_float2(hre, him);
        }
#pragma unroll
        for (int j = 0; j < 8; ++j) sc[j] = sn[j];
    }
}

// ---------------- inv: iDFT-x from 33 bins -> 32 cols, crop ------------------
__global__ __launch_bounds__(256)
void convssm_inv(const float2* __restrict__ Hhat,   // [t][bc][k][HY]
                 float* __restrict__ out)           // (T,B,C,32,32)
{
    __shared__ float2 Hl[32][34];

    const int blk = blockIdx.x;          // t*64 + bc
    const int tid = threadIdx.x;

    const float2* Hp = Hhat + (size_t)blk * KB * HY;
    for (int i = tid; i < KB * HY; i += 256) {
        const int k = i >> 5;
        const int y = i & 31;
        Hl[y][k] = Hp[(size_t)k * HY + y];
    }
    __syncthreads();

    const int y  = tid >> 3;
    const int n0 = (tid & 7) * 4;

    float acc[4], cr[4], sr[4], cb[4], sb[4];
#pragma unroll
    for (int j = 0; j < 4; ++j) {
        float s1, c1;
        __sincosf((float)(n0 + j) * THETA, &s1, &c1);
        cb[j] = c1; sb[j] = s1;     // rotate per k-step by e^{+2pi i n/64}
        cr[j] = c1; sr[j] = s1;     // state at k=1
        acc[j] = 0.f;
    }
    for (int k = 1; k < 32; ++k) {
        const float2 X = Hl[y][k];
#pragma unroll
        for (int j = 0; j < 4; ++j) {
            acc[j] = fmaf(X.x, cr[j], acc[j]);
            acc[j] = fmaf(-X.y, sr[j], acc[j]);
            const float cn = cr[j] * cb[j] - sr[j] * sb[j];
            const float sn = sr[j] * cb[j] + cr[j] * sb[j];
            cr[j] = cn; sr[j] = sn;
        }
    }
    const float x0  = Hl[y][0].x;
    const float x32 = Hl[y][32].x;
    float4 o;
    o.x = (x0 + (((n0 + 0) & 1) ? -x32 : x32) + 2.f * acc[0]) * 0.015625f;
    o.y = (x0 + (((n0 + 1) & 1) ? -x32 : x32) + 2.f * acc[1]) * 0.015625f;
    o.z = (x0 + (((n0 + 2) & 1) ? -x32 : x32) + 2.f * acc[2]) * 0.015625f;
    o.w = (x0 + (((n0 + 3) & 1) ? -x32 : x32) + 2.f * acc[3]) * 0.015625f;
    *(float4*)(out + (size_t)blk * (HW * HW) + y * HW + n0) = o;
}

// ---------------- Fallback (round-1 fused, known-correct, no ws) --------------
__global__ __launch_bounds__(256)
void convssm_scan_fused(const float* __restrict__ x_seq,
                        const float* __restrict__ A_k,
                        const float* __restrict__ B_k,
                        float* __restrict__ out)
{
    __shared__ float h0[N][N];
    __shared__ float h1[N][N];
    __shared__ float xsf[N][N];

    const int bc = blockIdx.x;
    const int b  = bc >> 5;
    const int c  = bc & 31;
    const int tid = threadIdx.x;
    const int x   = tid & 63;
    const int y0  = (tid >> 6) << 4;

    float a[9], bw[9];
#pragma unroll
    for (int i = 0; i < 9; ++i) { a[i] = A_k[c*9+i]; bw[i] = B_k[c*9+i]; }
#pragma unroll
    for (int r = 0; r < 16; ++r) { h0[y0+r][x] = 0.f; xsf[y0+r][x] = 0.f; }

    float (*hold)[N] = h0;
    float (*hnew)[N] = h1;
    const int xm1 = (x + 63) & 63, xm2 = (x + 62) & 63;
    const size_t img = (size_t)HW*HW, tstr = (size_t)NIMG*img;
    const float* xbase = x_seq + ((size_t)b*C_DIM + c)*img;
    float* obase = out + ((size_t)b*C_DIM + c)*img;
    const bool loader = (x < HW);

    for (int t = 0; t < T_STEPS; ++t) {
        if (loader) {
#pragma unroll
            for (int r = 0; r < 16; ++r) {
                int yy = y0 + r;
                if (yy < HW) xsf[yy][x] = xbase[(size_t)t*tstr + yy*HW + x];
            }
        }
        __syncthreads();
        const int ym1 = (y0 + N - 1) & 63, ym2 = (y0 + N - 2) & 63;
        float hr1c0 = hold[ym1][x], hr1c1 = hold[ym1][xm1], hr1c2 = hold[ym1][xm2];
        float hr2c0 = hold[ym2][x], hr2c1 = hold[ym2][xm1], hr2c2 = hold[ym2][xm2];
        float sr1c0 = xsf[ym1][x], sr1c1 = xsf[ym1][xm1], sr1c2 = xsf[ym1][xm2];
        float sr2c0 = xsf[ym2][x], sr2c1 = xsf[ym2][xm1], sr2c2 = xsf[ym2][xm2];
#pragma unroll
        for (int r = 0; r < 16; ++r) {
            const int yy = y0 + r;
            float hr0c0 = hold[yy][x], hr0c1 = hold[yy][xm1], hr0c2 = hold[yy][xm2];
            float sr0c0 = xsf[yy][x], sr0c1 = xsf[yy][xm1], sr0c2 = xsf[yy][xm2];
            float v = a[0]*hr0c0 + a[1]*hr0c1 + a[2]*hr0c2
                    + a[3]*hr1c0 + a[4]*hr1c1 + a[5]*hr1c2
                    + a[6]*hr2c0 + a[7]*hr2c1 + a[8]*hr2c2
                    + bw[0]*sr0c0 + bw[1]*sr0c1 + bw[2]*sr0c2
                    + bw[3]*sr1c0 + bw[4]*sr1c1 + bw[5]*sr1c2
                    + bw[6]*sr2c0 + bw[7]*sr2c1 + bw[8]*sr2c2;
            hnew[yy][x] = v;
            if (yy < HW && x < HW) obase[(size_t)t*tstr + yy*HW + x] = v;
            hr2c0=hr1c0; hr2c1=hr1c1; hr2c2=hr1c2;
            hr1c0=hr0c0; hr1c1=hr0c1; hr1c2=hr0c2;
            sr2c0=sr1c0; sr2c1=sr1c1; sr2c2=sr1c2;
            sr1c0=sr0c0; sr1c1=sr0c1; sr1c2=sr0c2;
        }
        __syncthreads();
        float (*tmp)[N] = hold; hold = hnew; hnew = tmp;
    }
}

extern "C" void kernel_launch(void* const* d_in, const int* in_sizes, int n_in,
                              void* d_out, int out_size, void* d_ws, size_t ws_size,
                              hipStream_t stream)
{
    const float* x_seq = (const float*)d_in[0];
    const float* A_k   = (const float*)d_in[1];
    const float* B_k   = (const float*)d_in[2];
    float* out = (float*)d_out;

    const size_t need = (S_SZ + H_SZ) * sizeof(float2);   // ~73.5 MB

    if (ws_size >= need) {
        float2* Shat = (float2*)d_ws;
        float2* Hhat = Shat + S_SZ;
        convssm_fwd<<<dim3(T_STEPS * NIMG), dim3(256), 0, stream>>>(
            x_seq, B_k, Shat);
        convssm_scanf<<<dim3(528), dim3(256), 0, stream>>>(
            Shat, A_k, Hhat);
        convssm_inv<<<dim3(T_STEPS * NIMG), dim3(256), 0, stream>>>(
            Hhat, out);
    } else {
        convssm_scan_fused<<<dim3(NIMG), dim3(256), 0, stream>>>(
            x_seq, A_k, B_k, out);
    }
}

// Round 13
// 61.898 us; speedup vs baseline: 1.5484x; 1.3184x over previous
//
#include <hip/hip_runtime.h>
#include <math.h>

// ConvSSM scan via 1-D frequency domain (rFFT along x only).
//   h_t = A (*) h_{t-1} + B (*) xpad_t, (*) = circular conv on 64x64.
// After rfft_x (64-point, 33 bins k):
//   hhat_t[y][k] = sum_{ky=0..2} Ahat[ky][k] * hhat_{t-1}[(y-ky)&63][k] + shat_t[y][k]
// fwd  (4096 blocks): radix-8 DIT DFT-x (n=8a+b, k=kg+8m; the bm-twiddle is a
//       compile-time 8th root -> free sign/swap or one sqrt2/2 scale) + Bhat
//       y-conv -> shat[bc][t][k][36]
// scan (528 blocks = 2112 waves): 64-step recurrence per (bc,k); lane y holds
//       hhat[y]; neighbors via __shfl; NO LDS, NO barriers; 8-deep prefetch.
// inv  (4096 blocks): iDFT-x from 33 bins -> 32 cols, crop, write out.

constexpr int T_STEPS = 64;
constexpr int B_DIM   = 2;
constexpr int C_DIM   = 32;
constexpr int HW      = 32;
constexpr int N       = 64;
constexpr int NIMG    = B_DIM * C_DIM;   // 64
constexpr int KB      = 33;              // rfft bins along x
constexpr int SY      = 36;              // padded y slots in shat (valid 0..33)
constexpr int HY      = 32;              // stored y rows in hhat (crop)

constexpr float THETA = 0.09817477042468103f;   // 2*pi/64
constexpr float R2H   = 0.70710678118654752f;   // sqrt(2)/2

constexpr size_t S_SZ = (size_t)NIMG * T_STEPS * KB * SY;
constexpr size_t H_SZ = (size_t)T_STEPS * NIMG * KB * HY;

// ---------------- fwd: radix-8 DFT-x + Bhat y-conv -> shat --------------------
__global__ __launch_bounds__(256)
void convssm_fwd(const float* __restrict__ x_seq,   // (T,B,C,32,32)
                 const float* __restrict__ B_k,     // (C,3,3)
                 float2* __restrict__ Shat)         // [bc][t][k][SY]
{
    __shared__ __align__(16) float xs[32][36];
    __shared__ float2 Xl[32][33];
    __shared__ float2 bh[3][33];

    const int blk = blockIdx.x;          // t*64 + bc
    const int t   = blk >> 6;
    const int bc  = blk & 63;
    const int c   = bc & 31;
    const int tid = threadIdx.x;

    // stage x image (coalesced float4)
    {
        const float4* xp = (const float4*)(x_seq + (size_t)blk * (HW * HW));
        const int y  = tid >> 3;
        const int x4 = (tid & 7) * 4;
        *(float4*)&xs[y][x4] = xp[tid];
    }
    // Bhat[ky][k] = sum_j B[ky][j] e^{-2pi i jk/64}
    if (tid < 99) {
        const int ky = tid / 33, k = tid - ky * 33;
        const float b0 = B_k[c * 9 + ky * 3 + 0];
        const float b1 = B_k[c * 9 + ky * 3 + 1];
        const float b2 = B_k[c * 9 + ky * 3 + 2];
        float s1, c1;
        __sincosf((float)k * THETA, &s1, &c1);
        const float c2 = c1 * c1 - s1 * s1, s2 = 2.f * c1 * s1;
        bh[ky][k] = make_float2(b0 + b1 * c1 + b2 * c2, -(b1 * s1 + b2 * s2));
    }
    __syncthreads();

    // Radix-8 DFT-x: thread = (row y, kg=0..7); bins k = kg + 8m, m=0..4.
    // X[kg+8m] = sum_b w1^b * t8^(b*m) * C_b,  C_b = sum_a x[8a+b] t1^a,
    // t1 = e^{-2pi i kg/8}, w1 = e^{-2pi i kg/64}, t8^(bm) compile-time.
    {
        const int y  = tid >> 3;
        const int kg = tid & 7;

        float xr[32];
#pragma unroll
        for (int j = 0; j < 8; ++j) {
            const float4 v = *(const float4*)&xs[y][j * 4];
            xr[4 * j]     = v.x; xr[4 * j + 1] = v.y;
            xr[4 * j + 2] = v.z; xr[4 * j + 3] = v.w;
        }

        float s8, c8, sw, cw;
        __sincosf((float)kg * (8.f * THETA), &s8, &c8);   // kg*2pi/8
        __sincosf((float)kg * THETA, &sw, &cw);           // kg*2pi/64
        const float t1r = c8, t1i = -s8;
        const float w1r = cw, w1i = -sw;
        const float t2r = t1r * t1r - t1i * t1i, t2i = 2.f * t1r * t1i;
        const float t3r = t2r * t1r - t2i * t1i, t3i = t2r * t1i + t2i * t1r;

        float Dr[8], Di[8];
        {
            float rr = 1.f, ri = 0.f;   // w1^b rotator
#pragma unroll
            for (int b = 0; b < 8; ++b) {
                const float cr = xr[b] + xr[b + 8] * t1r + xr[b + 16] * t2r + xr[b + 24] * t3r;
                const float ci = xr[b + 8] * t1i + xr[b + 16] * t2i + xr[b + 24] * t3i;
                Dr[b] = cr * rr - ci * ri;
                Di[b] = cr * ri + ci * rr;
                const float rrn = rr * w1r - ri * w1i;
                const float rin = rr * w1i + ri * w1r;
                rr = rrn; ri = rin;
            }
        }

#pragma unroll
        for (int m = 0; m < 5; ++m) {
            float Xr = Dr[0], Xi = Di[0];
#pragma unroll
            for (int b = 1; b < 8; ++b) {
                const int r = (b * m) & 7;
                switch (r) {
                case 0: Xr += Dr[b];                    Xi += Di[b];                    break;
                case 1: Xr += R2H * (Dr[b] + Di[b]);    Xi += R2H * (Di[b] - Dr[b]);    break;
                case 2: Xr += Di[b];                    Xi -= Dr[b];                    break;
                case 3: Xr += R2H * (Di[b] - Dr[b]);    Xi -= R2H * (Dr[b] + Di[b]);    break;
                case 4: Xr -= Dr[b];                    Xi -= Di[b];                    break;
                case 5: Xr -= R2H * (Dr[b] + Di[b]);    Xi += R2H * (Dr[b] - Di[b]);    break;
                case 6: Xr -= Di[b];                    Xi += Dr[b];                    break;
                case 7: Xr += R2H * (Dr[b] - Di[b]);    Xi += R2H * (Dr[b] + Di[b]);    break;
                }
            }
            const int k = kg + 8 * m;
            if (k < 33) Xl[y][k] = make_float2(Xr, Xi);
        }
    }
    __syncthreads();

    // shat[y][k] = sum_ky bh[ky][k] * Xl[y-ky][k], y in [0,34)
    float2* Sb = Shat + ((size_t)(bc * T_STEPS + t)) * KB * SY;
    for (int i = tid; i < 33 * 34; i += 256) {
        const int k = i / 34;
        const int y = i - 34 * k;
        float re = 0.f, im = 0.f;
#pragma unroll
        for (int ky = 0; ky < 3; ++ky) {
            const int yy = y - ky;
            if (yy >= 0 && yy < 32) {
                const float2 b = bh[ky][k];
                const float2 X = Xl[yy][k];
                re += b.x * X.x - b.y * X.y;
                im += b.x * X.y + b.y * X.x;
            }
        }
        Sb[(size_t)k * SY + y] = make_float2(re, im);
    }
}

// ---------------- scan: per-(bc,k) wave, 64 steps, no barriers ----------------
__global__ __launch_bounds__(256)
void convssm_scanf(const float2* __restrict__ Shat,  // [bc][t][k][SY]
                   const float* __restrict__ A_k,    // (C,3,3)
                   float2* __restrict__ Hhat)        // [t][bc][k][HY]
{
    const int tid = threadIdx.x;
    const int wid = blockIdx.x * 4 + (tid >> 6);   // 0..2111
    const int y   = tid & 63;
    const int bc  = wid / 33;
    const int k   = wid - 33 * bc;
    const int c   = bc & 31;

    float Are[3], Aim[3];
    {
        float s1, c1;
        __sincosf((float)k * THETA, &s1, &c1);
        const float c2 = c1 * c1 - s1 * s1, s2 = 2.f * c1 * s1;
#pragma unroll
        for (int ky = 0; ky < 3; ++ky) {
            const float a0 = A_k[c * 9 + ky * 3 + 0];
            const float a1 = A_k[c * 9 + ky * 3 + 1];
            const float a2 = A_k[c * 9 + ky * 3 + 2];
            Are[ky] = a0 + a1 * c1 + a2 * c2;
            Aim[ky] = -(a1 * s1 + a2 * s2);
        }
    }

    const int ym1 = (y + 63) & 63;
    const int ym2 = (y + 62) & 63;
    const bool sok = (y < 34);
    const bool hok = (y < HY);

    const float2* Sb = Shat + ((size_t)bc * T_STEPS) * KB * SY + (size_t)k * SY + y;
    const size_t sstep = (size_t)KB * SY;
    float2* Hb = Hhat + ((size_t)bc * KB + k) * HY + y;
    const size_t hstep = (size_t)NIMG * KB * HY;

    const float2 z2 = make_float2(0.f, 0.f);
    float hre = 0.f, him = 0.f;

    float2 sc[8], sn[8];
#pragma unroll
    for (int j = 0; j < 8; ++j)
        sc[j] = sok ? Sb[(size_t)j * sstep] : z2;

    for (int ob = 0; ob < 8; ++ob) {
        const int t0 = ob * 8;
        const bool pf = sok && (ob < 7);
#pragma unroll
        for (int j = 0; j < 8; ++j)
            sn[j] = pf ? Sb[(size_t)(t0 + 8 + j) * sstep] : z2;
#pragma unroll
        for (int j = 0; j < 8; ++j) {
            const float h1re = __shfl(hre, ym1, 64);
            const float h1im = __shfl(him, ym1, 64);
            const float h2re = __shfl(hre, ym2, 64);
            const float h2im = __shfl(him, ym2, 64);
            float nre = sc[j].x, nim = sc[j].y;
            nre += Are[0] * hre - Aim[0] * him;
            nim += Are[0] * him + Aim[0] * hre;
            nre += Are[1] * h1re - Aim[1] * h1im;
            nim += Are[1] * h1im + Aim[1] * h1re;
            nre += Are[2] * h2re - Aim[2] * h2im;
            nim += Are[2] * h2im + Aim[2] * h2re;
            hre = nre; him = nim;
            if (hok) Hb[(size_t)(t0 + j) * hstep] = make_float2(hre, him);
        }
#pragma unroll
        for (int j = 0; j < 8; ++j) sc[j] = sn[j];
    }
}

// ---------------- inv: iDFT-x from 33 bins -> 32 cols, crop ------------------
__global__ __launch_bounds__(256)
void convssm_inv(const float2* __restrict__ Hhat,   // [t][bc][k][HY]
                 float* __restrict__ out)           // (T,B,C,32,32)
{
    __shared__ float2 Hl[32][34];

    const int blk = blockIdx.x;          // t*64 + bc
    const int tid = threadIdx.x;

    const float2* Hp = Hhat + (size_t)blk * KB * HY;
    for (int i = tid; i < KB * HY; i += 256) {
        const int k = i >> 5;
        const int y = i & 31;
        Hl[y][k] = Hp[(size_t)k * HY + y];
    }
    __syncthreads();

    const int y  = tid >> 3;
    const int n0 = (tid & 7) * 4;

    float acc[4], cr[4], sr[4], cb[4], sb[4];
#pragma unroll
    for (int j = 0; j < 4; ++j) {
        float s1, c1;
        __sincosf((float)(n0 + j) * THETA, &s1, &c1);
        cb[j] = c1; sb[j] = s1;
        cr[j] = c1; sr[j] = s1;
        acc[j] = 0.f;
    }
    for (int k = 1; k < 32; ++k) {
        const float2 X = Hl[y][k];
#pragma unroll
        for (int j = 0; j < 4; ++j) {
            acc[j] = fmaf(X.x, cr[j], acc[j]);
            acc[j] = fmaf(-X.y, sr[j], acc[j]);
            const float cn = cr[j] * cb[j] - sr[j] * sb[j];
            const float sn = sr[j] * cb[j] + cr[j] * sb[j];
            cr[j] = cn; sr[j] = sn;
        }
    }
    const float x0  = Hl[y][0].x;
    const float x32 = Hl[y][32].x;
    float4 o;
    o.x = (x0 + (((n0 + 0) & 1) ? -x32 : x32) + 2.f * acc[0]) * 0.015625f;
    o.y = (x0 + (((n0 + 1) & 1) ? -x32 : x32) + 2.f * acc[1]) * 0.015625f;
    o.z = (x0 + (((n0 + 2) & 1) ? -x32 : x32) + 2.f * acc[2]) * 0.015625f;
    o.w = (x0 + (((n0 + 3) & 1) ? -x32 : x32) + 2.f * acc[3]) * 0.015625f;
    *(float4*)(out + (size_t)blk * (HW * HW) + y * HW + n0) = o;
}

// ---------------- Fallback (round-1 fused, known-correct, no ws) --------------
__global__ __launch_bounds__(256)
void convssm_scan_fused(const float* __restrict__ x_seq,
                        const float* __restrict__ A_k,
                        const float* __restrict__ B_k,
                        float* __restrict__ out)
{
    __shared__ float h0[N][N];
    __shared__ float h1[N][N];
    __shared__ float xsf[N][N];

    const int bc = blockIdx.x;
    const int b  = bc >> 5;
    const int c  = bc & 31;
    const int tid = threadIdx.x;
    const int x   = tid & 63;
    const int y0  = (tid >> 6) << 4;

    float a[9], bw[9];
#pragma unroll
    for (int i = 0; i < 9; ++i) { a[i] = A_k[c*9+i]; bw[i] = B_k[c*9+i]; }
#pragma unroll
    for (int r = 0; r < 16; ++r) { h0[y0+r][x] = 0.f; xsf[y0+r][x] = 0.f; }

    float (*hold)[N] = h0;
    float (*hnew)[N] = h1;
    const int xm1 = (x + 63) & 63, xm2 = (x + 62) & 63;
    const size_t img = (size_t)HW*HW, tstr = (size_t)NIMG*img;
    const float* xbase = x_seq + ((size_t)b*C_DIM + c)*img;
    float* obase = out + ((size_t)b*C_DIM + c)*img;
    const bool loader = (x < HW);

    for (int t = 0; t < T_STEPS; ++t) {
        if (loader) {
#pragma unroll
            for (int r = 0; r < 16; ++r) {
                int yy = y0 + r;
                if (yy < HW) xsf[yy][x] = xbase[(size_t)t*tstr + yy*HW + x];
            }
        }
        __syncthreads();
        const int ym1 = (y0 + N - 1) & 63, ym2 = (y0 + N - 2) & 63;
        float hr1c0 = hold[ym1][x], hr1c1 = hold[ym1][xm1], hr1c2 = hold[ym1][xm2];
        float hr2c0 = hold[ym2][x], hr2c1 = hold[ym2][xm1], hr2c2 = hold[ym2][xm2];
        float sr1c0 = xsf[ym1][x], sr1c1 = xsf[ym1][xm1], sr1c2 = xsf[ym1][xm2];
        float sr2c0 = xsf[ym2][x], sr2c1 = xsf[ym2][xm1], sr2c2 = xsf[ym2][xm2];
#pragma unroll
        for (int r = 0; r < 16; ++r) {
            const int yy = y0 + r;
            float hr0c0 = hold[yy][x], hr0c1 = hold[yy][xm1], hr0c2 = hold[yy][xm2];
            float sr0c0 = xsf[yy][x], sr0c1 = xsf[yy][xm1], sr0c2 = xsf[yy][xm2];
            float v = a[0]*hr0c0 + a[1]*hr0c1 + a[2]*hr0c2
                    + a[3]*hr1c0 + a[4]*hr1c1 + a[5]*hr1c2
                    + a[6]*hr2c0 + a[7]*hr2c1 + a[8]*hr2c2
                    + bw[0]*sr0c0 + bw[1]*sr0c1 + bw[2]*sr0c2
                    + bw[3]*sr1c0 + bw[4]*sr1c1 + bw[5]*sr1c2
                    + bw[6]*sr2c0 + bw[7]*sr2c1 + bw[8]*sr2c2;
            hnew[yy][x] = v;
            if (yy < HW && x < HW) obase[(size_t)t*tstr + yy*HW + x] = v;
            hr2c0=hr1c0; hr2c1=hr1c1; hr2c2=hr1c2;
            hr1c0=hr0c0; hr1c1=hr0c1; hr1c2=hr0c2;
            sr2c0=sr1c0; sr2c1=sr1c1; sr2c2=sr1c2;
            sr1c0=sr0c0; sr1c1=sr0c1; sr1c2=sr0c2;
        }
        __syncthreads();
        float (*tmp)[N] = hold; hold = hnew; hnew = tmp;
    }
}

extern "C" void kernel_launch(void* const* d_in, const int* in_sizes, int n_in,
                              void* d_out, int out_size, void* d_ws, size_t ws_size,
                              hipStream_t stream)
{
    const float* x_seq = (const float*)d_in[0];
    const float* A_k   = (const float*)d_in[1];
    const float* B_k   = (const float*)d_in[2];
    float* out = (float*)d_out;

    const size_t need = (S_SZ + H_SZ) * sizeof(float2);   // ~73.5 MB

    if (ws_size >= need) {
        float2* Shat = (float2*)d_ws;
        float2* Hhat = Shat + S_SZ;
        convssm_fwd<<<dim3(T_STEPS * NIMG), dim3(256), 0, stream>>>(
            x_seq, B_k, Shat);
        convssm_scanf<<<dim3(528), dim3(256), 0, stream>>>(
            Shat, A_k, Hhat);
        convssm_inv<<<dim3(T_STEPS * NIMG), dim3(256), 0, stream>>>(
            Hhat, out);
    } else {
        convssm_scan_fused<<<dim3(NIMG), dim3(256), 0, stream>>>(
            x_seq, A_k, B_k, out);
    }
}

// Round 14
// 60.901 us; speedup vs baseline: 1.5737x; 1.0164x over previous
//
#include <hip/hip_runtime.h>
#include <math.h>

// ConvSSM scan via 1-D frequency domain (rFFT along x only).
//   h_t = A (*) h_{t-1} + B (*) xpad_t, (*) = circular conv on 64x64.
// After rfft_x (64-point, 33 bins k):
//   hhat_t[y][k] = sum_{ky=0..2} Ahat[ky][k] * hhat_{t-1}[(y-ky)&63][k] + shat_t[y][k]
// fwd  (4096 blocks): radix-8 DIT DFT-x (n=8a+b, k=kg+8m; the bm-twiddle is a
//       compile-time 8th root -> free sign/swap or one sqrt2/2 scale) + Bhat
//       y-conv -> shat[bc][t][k][36]
// scan (528 blocks = 2112 waves): 64-step recurrence per (bc,k); lane y holds
//       hhat[y]; neighbors via __shfl; NO LDS, NO barriers; 8-deep prefetch.
// inv  (4096 blocks): iDFT-x from 33 bins -> 32 cols, crop, write out.

constexpr int T_STEPS = 64;
constexpr int B_DIM   = 2;
constexpr int C_DIM   = 32;
constexpr int HW      = 32;
constexpr int N       = 64;
constexpr int NIMG    = B_DIM * C_DIM;   // 64
constexpr int KB      = 33;              // rfft bins along x
constexpr int SY      = 36;              // padded y slots in shat (valid 0..33)
constexpr int HY      = 32;              // stored y rows in hhat (crop)

constexpr float THETA = 0.09817477042468103f;   // 2*pi/64
constexpr float R2H   = 0.70710678118654752f;   // sqrt(2)/2

constexpr size_t S_SZ = (size_t)NIMG * T_STEPS * KB * SY;
constexpr size_t H_SZ = (size_t)T_STEPS * NIMG * KB * HY;

// ---------------- fwd: radix-8 DFT-x + Bhat y-conv -> shat --------------------
__global__ __launch_bounds__(256)
void convssm_fwd(const float* __restrict__ x_seq,   // (T,B,C,32,32)
                 const float* __restrict__ B_k,     // (C,3,3)
                 float2* __restrict__ Shat)         // [bc][t][k][SY]
{
    __shared__ __align__(16) float xs[32][36];
    __shared__ float2 Xl[32][33];
    __shared__ float2 bh[3][33];

    const int blk = blockIdx.x;          // t*64 + bc
    const int t   = blk >> 6;
    const int bc  = blk & 63;
    const int c   = bc & 31;
    const int tid = threadIdx.x;

    // stage x image (coalesced float4)
    {
        const float4* xp = (const float4*)(x_seq + (size_t)blk * (HW * HW));
        const int y  = tid >> 3;
        const int x4 = (tid & 7) * 4;
        *(float4*)&xs[y][x4] = xp[tid];
    }
    // Bhat[ky][k] = sum_j B[ky][j] e^{-2pi i jk/64}
    if (tid < 99) {
        const int ky = tid / 33, k = tid - ky * 33;
        const float b0 = B_k[c * 9 + ky * 3 + 0];
        const float b1 = B_k[c * 9 + ky * 3 + 1];
        const float b2 = B_k[c * 9 + ky * 3 + 2];
        float s1, c1;
        __sincosf((float)k * THETA, &s1, &c1);
        const float c2 = c1 * c1 - s1 * s1, s2 = 2.f * c1 * s1;
        bh[ky][k] = make_float2(b0 + b1 * c1 + b2 * c2, -(b1 * s1 + b2 * s2));
    }
    __syncthreads();

    // Radix-8 DFT-x: thread = (row y, kg=0..7); bins k = kg + 8m, m=0..4.
    // X[kg+8m] = sum_b w1^b * t8^(b*m) * C_b,  C_b = sum_a x[8a+b] t1^a,
    // t1 = e^{-2pi i kg/8}, w1 = e^{-2pi i kg/64}, t8^(bm) compile-time.
    {
        const int y  = tid >> 3;
        const int kg = tid & 7;

        float xr[32];
#pragma unroll
        for (int j = 0; j < 8; ++j) {
            const float4 v = *(const float4*)&xs[y][j * 4];
            xr[4 * j]     = v.x; xr[4 * j + 1] = v.y;
            xr[4 * j + 2] = v.z; xr[4 * j + 3] = v.w;
        }

        float s8, c8, sw, cw;
        __sincosf((float)kg * (8.f * THETA), &s8, &c8);   // kg*2pi/8
        __sincosf((float)kg * THETA, &sw, &cw);           // kg*2pi/64
        const float t1r = c8, t1i = -s8;
        const float w1r = cw, w1i = -sw;
        const float t2r = t1r * t1r - t1i * t1i, t2i = 2.f * t1r * t1i;
        const float t3r = t2r * t1r - t2i * t1i, t3i = t2r * t1i + t2i * t1r;

        float Dr[8], Di[8];
        {
            float rr = 1.f, ri = 0.f;   // w1^b rotator
#pragma unroll
            for (int b = 0; b < 8; ++b) {
                const float cr = xr[b] + xr[b + 8] * t1r + xr[b + 16] * t2r + xr[b + 24] * t3r;
                const float ci = xr[b + 8] * t1i + xr[b + 16] * t2i + xr[b + 24] * t3i;
                Dr[b] = cr * rr - ci * ri;
                Di[b] = cr * ri + ci * rr;
                const float rrn = rr * w1r - ri * w1i;
                const float rin = rr * w1i + ri * w1r;
                rr = rrn; ri = rin;
            }
        }

#pragma unroll
        for (int m = 0; m < 5; ++m) {
            float Xr = Dr[0], Xi = Di[0];
#pragma unroll
            for (int b = 1; b < 8; ++b) {
                const int r = (b * m) & 7;
                switch (r) {
                case 0: Xr += Dr[b];                    Xi += Di[b];                    break;
                case 1: Xr += R2H * (Dr[b] + Di[b]);    Xi += R2H * (Di[b] - Dr[b]);    break;
                case 2: Xr += Di[b];                    Xi -= Dr[b];                    break;
                case 3: Xr += R2H * (Di[b] - Dr[b]);    Xi -= R2H * (Dr[b] + Di[b]);    break;
                case 4: Xr -= Dr[b];                    Xi -= Di[b];                    break;
                case 5: Xr -= R2H * (Dr[b] + Di[b]);    Xi += R2H * (Dr[b] - Di[b]);    break;
                case 6: Xr -= Di[b];                    Xi += Dr[b];                    break;
                case 7: Xr += R2H * (Dr[b] - Di[b]);    Xi += R2H * (Dr[b] + Di[b]);    break;
                }
            }
            const int k = kg + 8 * m;
            if (k < 33) Xl[y][k] = make_float2(Xr, Xi);
        }
    }
    __syncthreads();

    // shat[y][k] = sum_ky bh[ky][k] * Xl[y-ky][k], y in [0,34)
    float2* Sb = Shat + ((size_t)(bc * T_STEPS + t)) * KB * SY;
    for (int i = tid; i < 33 * 34; i += 256) {
        const int k = i / 34;
        const int y = i - 34 * k;
        float re = 0.f, im = 0.f;
#pragma unroll
        for (int ky = 0; ky < 3; ++ky) {
            const int yy = y - ky;
            if (yy >= 0 && yy < 32) {
                const float2 b = bh[ky][k];
                const float2 X = Xl[yy][k];
                re += b.x * X.x - b.y * X.y;
                im += b.x * X.y + b.y * X.x;
            }
        }
        Sb[(size_t)k * SY + y] = make_float2(re, im);
    }
}

// ---------------- scan: per-(bc,k) wave, 64 steps, no barriers ----------------
__global__ __launch_bounds__(256)
void convssm_scanf(const float2* __restrict__ Shat,  // [bc][t][k][SY]
                   const float* __restrict__ A_k,    // (C,3,3)
                   float2* __restrict__ Hhat)        // [t][bc][k][HY]
{
    const int tid = threadIdx.x;
    const int wid = blockIdx.x * 4 + (tid >> 6);   // 0..2111
    const int y   = tid & 63;
    const int bc  = wid / 33;
    const int k   = wid - 33 * bc;
    const int c   = bc & 31;

    float Are[3], Aim[3];
    {
        float s1, c1;
        __sincosf((float)k * THETA, &s1, &c1);
        const float c2 = c1 * c1 - s1 * s1, s2 = 2.f * c1 * s1;
#pragma unroll
        for (int ky = 0; ky < 3; ++ky) {
            const float a0 = A_k[c * 9 + ky * 3 + 0];
            const float a1 = A_k[c * 9 + ky * 3 + 1];
            const float a2 = A_k[c * 9 + ky * 3 + 2];
            Are[ky] = a0 + a1 * c1 + a2 * c2;
            Aim[ky] = -(a1 * s1 + a2 * s2);
        }
    }

    const int ym1 = (y + 63) & 63;
    const int ym2 = (y + 62) & 63;
    const bool sok = (y < 34);
    const bool hok = (y < HY);

    const float2* Sb = Shat + ((size_t)bc * T_STEPS) * KB * SY + (size_t)k * SY + y;
    const size_t sstep = (size_t)KB * SY;
    float2* Hb = Hhat + ((size_t)bc * KB + k) * HY + y;
    const size_t hstep = (size_t)NIMG * KB * HY;

    const float2 z2 = make_float2(0.f, 0.f);
    float hre = 0.f, him = 0.f;

    float2 sc[8], sn[8];
#pragma unroll
    for (int j = 0; j < 8; ++j)
        sc[j] = sok ? Sb[(size_t)j * sstep] : z2;

    for (int ob = 0; ob < 8; ++ob) {
        const int t0 = ob * 8;
        const bool pf = sok && (ob < 7);
#pragma unroll
        for (int j = 0; j < 8; ++j)
            sn[j] = pf ? Sb[(size_t)(t0 + 8 + j) * sstep] : z2;
#pragma unroll
        for (int j = 0; j < 8; ++j) {
            const float h1re = __shfl(hre, ym1, 64);
            const float h1im = __shfl(him, ym1, 64);
            const float h2re = __shfl(hre, ym2, 64);
            const float h2im = __shfl(him, ym2, 64);
            float nre = sc[j].x, nim = sc[j].y;
            nre += Are[0] * hre - Aim[0] * him;
            nim += Are[0] * him + Aim[0] * hre;
            nre += Are[1] * h1re - Aim[1] * h1im;
            nim += Are[1] * h1im + Aim[1] * h1re;
            nre += Are[2] * h2re - Aim[2] * h2im;
            nim += Are[2] * h2im + Aim[2] * h2re;
            hre = nre; him = nim;
            if (hok) Hb[(size_t)(t0 + j) * hstep] = make_float2(hre, him);
        }
#pragma unroll
        for (int j = 0; j < 8; ++j) sc[j] = sn[j];
    }
}

// ---------------- inv: iDFT-x from 33 bins -> 32 cols, crop ------------------
__global__ __launch_bounds__(256)
void convssm_inv(const float2* __restrict__ Hhat,   // [t][bc][k][HY]
                 float* __restrict__ out)           // (T,B,C,32,32)
{
    __shared__ float2 Hl[32][34];

    const int blk = blockIdx.x;          // t*64 + bc
    const int tid = threadIdx.x;

    const float2* Hp = Hhat + (size_t)blk * KB * HY;
    for (int i = tid; i < KB * HY; i += 256) {
        const int k = i >> 5;
        const int y = i & 31;
        Hl[y][k] = Hp[(size_t)k * HY + y];
    }
    __syncthreads();

    const int y  = tid >> 3;
    const int n0 = (tid & 7) * 4;

    float acc[4], cr[4], sr[4], cb[4], sb[4];
#pragma unroll
    for (int j = 0; j < 4; ++j) {
        float s1, c1;
        __sincosf((float)(n0 + j) * THETA, &s1, &c1);
        cb[j] = c1; sb[j] = s1;
        cr[j] = c1; sr[j] = s1;
        acc[j] = 0.f;
    }
    for (int k = 1; k < 32; ++k) {
        const float2 X = Hl[y][k];
#pragma unroll
        for (int j = 0; j < 4; ++j) {
            acc[j] = fmaf(X.x, cr[j], acc[j]);
            acc[j] = fmaf(-X.y, sr[j], acc[j]);
            const float cn = cr[j] * cb[j] - sr[j] * sb[j];
            const float sn = sr[j] * cb[j] + cr[j] * sb[j];
            cr[j] = cn; sr[j] = sn;
        }
    }
    const float x0  = Hl[y][0].x;
    const float x32 = Hl[y][32].x;
    float4 o;
    o.x = (x0 + (((n0 + 0) & 1) ? -x32 : x32) + 2.f * acc[0]) * 0.015625f;
    o.y = (x0 + (((n0 + 1) & 1) ? -x32 : x32) + 2.f * acc[1]) * 0.015625f;
    o.z = (x0 + (((n0 + 2) & 1) ? -x32 : x32) + 2.f * acc[2]) * 0.015625f;
    o.w = (x0 + (((n0 + 3) & 1) ? -x32 : x32) + 2.f * acc[3]) * 0.015625f;
    *(float4*)(out + (size_t)blk * (HW * HW) + y * HW + n0) = o;
}

// ---------------- Fallback (round-1 fused, known-correct, no ws) --------------
__global__ __launch_bounds__(256)
void convssm_scan_fused(const float* __restrict__ x_seq,
                        const float* __restrict__ A_k,
                        const float* __restrict__ B_k,
                        float* __restrict__ out)
{
    __shared__ float h0[N][N];
    __shared__ float h1[N][N];
    __shared__ float xsf[N][N];

    const int bc = blockIdx.x;
    const int b  = bc >> 5;
    const int c  = bc & 31;
    const int tid = threadIdx.x;
    const int x   = tid & 63;
    const int y0  = (tid >> 6) << 4;

    float a[9], bw[9];
#pragma unroll
    for (int i = 0; i < 9; ++i) { a[i] = A_k[c*9+i]; bw[i] = B_k[c*9+i]; }
#pragma unroll
    for (int r = 0; r < 16; ++r) { h0[y0+r][x] = 0.f; xsf[y0+r][x] = 0.f; }

    float (*hold)[N] = h0;
    float (*hnew)[N] = h1;
    const int xm1 = (x + 63) & 63, xm2 = (x + 62) & 63;
    const size_t img = (size_t)HW*HW, tstr = (size_t)NIMG*img;
    const float* xbase = x_seq + ((size_t)b*C_DIM + c)*img;
    float* obase = out + ((size_t)b*C_DIM + c)*img;
    const bool loader = (x < HW);

    for (int t = 0; t < T_STEPS; ++t) {
        if (loader) {
#pragma unroll
            for (int r = 0; r < 16; ++r) {
                int yy = y0 + r;
                if (yy < HW) xsf[yy][x] = xbase[(size_t)t*tstr + yy*HW + x];
            }
        }
        __syncthreads();
        const int ym1 = (y0 + N - 1) & 63, ym2 = (y0 + N - 2) & 63;
        float hr1c0 = hold[ym1][x], hr1c1 = hold[ym1][xm1], hr1c2 = hold[ym1][xm2];
        float hr2c0 = hold[ym2][x], hr2c1 = hold[ym2][xm1], hr2c2 = hold[ym2][xm2];
        float sr1c0 = xsf[ym1][x], sr1c1 = xsf[ym1][xm1], sr1c2 = xsf[ym1][xm2];
        float sr2c0 = xsf[ym2][x], sr2c1 = xsf[ym2][xm1], sr2c2 = xsf[ym2][xm2];
#pragma unroll
        for (int r = 0; r < 16; ++r) {
            const int yy = y0 + r;
            float hr0c0 = hold[yy][x], hr0c1 = hold[yy][xm1], hr0c2 = hold[yy][xm2];
            float sr0c0 = xsf[yy][x], sr0c1 = xsf[yy][xm1], sr0c2 = xsf[yy][xm2];
            float v = a[0]*hr0c0 + a[1]*hr0c1 + a[2]*hr0c2
                    + a[3]*hr1c0 + a[4]*hr1c1 + a[5]*hr1c2
                    + a[6]*hr2c0 + a[7]*hr2c1 + a[8]*hr2c2
                    + bw[0]*sr0c0 + bw[1]*sr0c1 + bw[2]*sr0c2
                    + bw[3]*sr1c0 + bw[4]*sr1c1 + bw[5]*sr1c2
                    + bw[6]*sr2c0 + bw[7]*sr2c1 + bw[8]*sr2c2;
            hnew[yy][x] = v;
            if (yy < HW && x < HW) obase[(size_t)t*tstr + yy*HW + x] = v;
            hr2c0=hr1c0; hr2c1=hr1c1; hr2c2=hr1c2;
            hr1c0=hr0c0; hr1c1=hr0c1; hr1c2=hr0c2;
            sr2c0=sr1c0; sr2c1=sr1c1; sr2c2=sr1c2;
            sr1c0=sr0c0; sr1c1=sr0c1; sr1c2=sr0c2;
        }
        __syncthreads();
        float (*tmp)[N] = hold; hold = hnew; hnew = tmp;
    }
}

extern "C" void kernel_launch(void* const* d_in, const int* in_sizes, int n_in,
                              void* d_out, int out_size, void* d_ws, size_t ws_size,
                              hipStream_t stream)
{
    const float* x_seq = (const float*)d_in[0];
    const float* A_k   = (const float*)d_in[1];
    const float* B_k   = (const float*)d_in[2];
    float* out = (float*)d_out;

    const size_t need = (S_SZ + H_SZ) * sizeof(float2);   // ~73.5 MB

    if (ws_size >= need) {
        float2* Shat = (float2*)d_ws;
        float2* Hhat = Shat + S_SZ;
        convssm_fwd<<<dim3(T_STEPS * NIMG), dim3(256), 0, stream>>>(
            x_seq, B_k, Shat);
        convssm_scanf<<<dim3(528), dim3(256), 0, stream>>>(
            Shat, A_k, Hhat);
        convssm_inv<<<dim3(T_STEPS * NIMG), dim3(256), 0, stream>>>(
            Hhat, out);
    } else {
        convssm_scan_fused<<<dim3(NIMG), dim3(256), 0, stream>>>(
            x_seq, A_k, B_k, out);
    }
}